// Round 10
// baseline (92.234 us; speedup 1.0000x reference)
//
#include <hip/hip_runtime.h>

#define BATCH 4096
#define DIM   128
#define NT    32   // 4096 / 128 tiles per dimension
// TEMP = 0.25 -> 1/T = 4; 4*log2(e):
#define EXP_SCALE 5.770780163555854f

typedef __bf16 bf16_t;
typedef __bf16 bf16x8 __attribute__((ext_vector_type(8)));
typedef float  f32x4  __attribute__((ext_vector_type(4)));

// ---------------------------------------------------------------------------
// Kernel A: per row k, normalize emb_i[k] and emb_j[k] (fp32 math), write
// bf16 z_i, z_j to workspace, pos[k] = cos-sim in fp32. One wave per row.
// Block 0 zeroes out[0] (accumulated by K3's one-atomic-per-block).
// NO denom zeroing needed this round: K2 writes deterministic partials.
// ---------------------------------------------------------------------------
__global__ __launch_bounds__(256) void normalize_kernel(
    const float* __restrict__ emb_i, const float* __restrict__ emb_j,
    bf16_t* __restrict__ zi, bf16_t* __restrict__ zj, float* __restrict__ pos,
    float* __restrict__ out)
{
    if (blockIdx.x == 0 && threadIdx.x == 0) out[0] = 0.0f;

    int wave = threadIdx.x >> 6;
    int lane = threadIdx.x & 63;
    int k = blockIdx.x * 4 + wave;

    const float2* ei = (const float2*)(emb_i + (size_t)k * DIM);
    const float2* ej = (const float2*)(emb_j + (size_t)k * DIM);
    float2 a = ei[lane];
    float2 b = ej[lane];

    float sii = a.x * a.x + a.y * a.y;
    float sjj = b.x * b.x + b.y * b.y;
    float sij = a.x * b.x + a.y * b.y;
#pragma unroll
    for (int m = 1; m < 64; m <<= 1) {
        sii += __shfl_xor(sii, m);
        sjj += __shfl_xor(sjj, m);
        sij += __shfl_xor(sij, m);
    }
    float inv_i = 1.0f / fmaxf(sqrtf(sii), 1e-12f);
    float inv_j = 1.0f / fmaxf(sqrtf(sjj), 1e-12f);

    struct bf16_2 { bf16_t x, y; };
    bf16_2 pi, pj;
    pi.x = (bf16_t)(a.x * inv_i);  pi.y = (bf16_t)(a.y * inv_i);
    pj.x = (bf16_t)(b.x * inv_j);  pj.y = (bf16_t)(b.y * inv_j);
    ((bf16_2*)(zi + (size_t)k * DIM))[lane] = pi;
    ((bf16_2*)(zj + (size_t)k * DIM))[lane] = pj;

    if (lane == 0) pos[k] = sij * inv_i * inv_j;
}

// ---------------------------------------------------------------------------
// Kernel B: 128x128 tile of S = Zi * Zj^T per block (grid 32x32).
// Staging/MFMA/epilogue-math byte-identical to the proven 74.6/74.4 body
// (single-stage 72KB LDS; padded-136 rows; no swizzle; no fences; no
// launch-bounds VGPR cap). SINGLE CHANGE: output path. The baseline issues
// 262K device-scope atomicAdds (32 serialized RMWs per denom address at
// the cross-XCD coherence point). Here each block writes its 128 row-sums
// and 128 col-sums to deterministic partial arrays rowP[tj][4096],
// colP[ti][4096] with ONE coalesced 128-float store each (row sums routed
// through LDS to coalesce). This is the clean test of the atomic-cost
// hypothesis: R2's partials test was confounded by a 128-VGPR cap (spill)
// and a different wave decomposition.
// ---------------------------------------------------------------------------
__global__ __launch_bounds__(256) void gemm_exp_kernel(
    const bf16_t* __restrict__ zi, const bf16_t* __restrict__ zj,
    float* __restrict__ rowP,   // [NT][BATCH], indexed [tj][global row]
    float* __restrict__ colP)   // [NT][BATCH], indexed [ti][global col]
{
    __shared__ __align__(16) bf16_t zi_s[128][136];
    __shared__ __align__(16) bf16_t zj_s[128][136];
    __shared__ float colRed[4][128];
    __shared__ float rowRed[128];

    const int tid = threadIdx.x;
    const int ti = blockIdx.x, tj = blockIdx.y;

    // Stage 128x128 bf16 of each matrix: 2048 16B-chunks / matrix, 8 iters.
#pragma unroll
    for (int it = 0; it < 8; ++it) {
        int c = it * 256 + tid;
        int row = c >> 4;          // 16 chunks per row
        int col = (c & 15) << 3;   // 8 bf16 per chunk
        *(uint4*)&zi_s[row][col] =
            *(const uint4*)(zi + ((size_t)(ti * 128 + row)) * DIM + col);
        *(uint4*)&zj_s[row][col] =
            *(const uint4*)(zj + ((size_t)(tj * 128 + row)) * DIM + col);
    }
    __syncthreads();

    const int wave = tid >> 6;
    const int lane = tid & 63;
    const int l15  = lane & 15;
    const int quad = lane >> 4;

    const f32x4 vzero = {0.f, 0.f, 0.f, 0.f};
    f32x4 acc[2][8];
#pragma unroll
    for (int rt = 0; rt < 2; ++rt)
#pragma unroll
        for (int ct = 0; ct < 8; ++ct) acc[rt][ct] = vzero;

#pragma unroll
    for (int ks = 0; ks < 4; ++ks) {
        int k0 = ks * 32 + quad * 8;
        bf16x8 afrag[2], bfrag[8];
#pragma unroll
        for (int rt = 0; rt < 2; ++rt)
            afrag[rt] = *(const bf16x8*)&zi_s[(wave * 2 + rt) * 16 + l15][k0];
#pragma unroll
        for (int ct = 0; ct < 8; ++ct)
            bfrag[ct] = *(const bf16x8*)&zj_s[ct * 16 + l15][k0];
#pragma unroll
        for (int rt = 0; rt < 2; ++rt)
#pragma unroll
            for (int ct = 0; ct < 8; ++ct)
                acc[rt][ct] = __builtin_amdgcn_mfma_f32_16x16x32_bf16(
                    afrag[rt], bfrag[ct], acc[rt][ct], 0, 0, 0);
    }

    // Epilogue: exp and partial sums.
    float rowPart[2][4] = {{0.f, 0.f, 0.f, 0.f}, {0.f, 0.f, 0.f, 0.f}};
    float colPart[8]    = {0.f, 0.f, 0.f, 0.f, 0.f, 0.f, 0.f, 0.f};
#pragma unroll
    for (int rt = 0; rt < 2; ++rt)
#pragma unroll
        for (int ct = 0; ct < 8; ++ct)
#pragma unroll
            for (int r = 0; r < 4; ++r) {
                float e = exp2f(acc[rt][ct][r] * EXP_SCALE);
                rowPart[rt][r] += e;   // row = (wave*2+rt)*16 + quad*4 + r
                colPart[ct]    += e;   // col = ct*16 + l15
            }

    // Row sums: each wave's rows see all 128 tile columns; 16-lane shfl
    // reduce completes them. Route through LDS for one coalesced store.
#pragma unroll
    for (int rt = 0; rt < 2; ++rt)
#pragma unroll
        for (int r = 0; r < 4; ++r) {
            float v = rowPart[rt][r];
            v += __shfl_xor(v, 1);
            v += __shfl_xor(v, 2);
            v += __shfl_xor(v, 4);
            v += __shfl_xor(v, 8);
            if (l15 == 0)
                rowRed[(wave * 2 + rt) * 16 + quad * 4 + r] = v;
        }

    // Col sums: quad shfl-reduce, then cross-wave LDS reduce.
#pragma unroll
    for (int ct = 0; ct < 8; ++ct) {
        float v = colPart[ct];
        v += __shfl_xor(v, 16);
        v += __shfl_xor(v, 32);
        if (quad == 0) colRed[wave][ct * 16 + l15] = v;
    }
    __syncthreads();
    if (tid < 128) {
        rowP[(size_t)tj * BATCH + ti * 128 + tid] = rowRed[tid];
        float s = colRed[0][tid] + colRed[1][tid] + colRed[2][tid] + colRed[3][tid];
        colP[(size_t)ti * BATCH + tj * 128 + tid] = s;
    }
}

// ---------------------------------------------------------------------------
// Kernel C: denom_k = sum of 32 tile partials per array (coalesced across
// threads, 64 independent loads per thread); loss contribution
// log(rowDenom_k) + log(colDenom_k) - 8*pos_k. 16 blocks x 256 threads;
// one atomicAdd per block into out[0] (zeroed by K1).
// ---------------------------------------------------------------------------
__global__ __launch_bounds__(256) void finalize_kernel(
    const float* __restrict__ rowP, const float* __restrict__ colP,
    const float* __restrict__ pos, float* __restrict__ out)
{
    const int k = blockIdx.x * 256 + threadIdx.x;
    float rd = 0.f, cd = 0.f;
#pragma unroll
    for (int t = 0; t < NT; ++t) {
        rd += rowP[(size_t)t * BATCH + k];
        cd += colP[(size_t)t * BATCH + k];
    }
    float v = logf(rd) + logf(cd) - 8.0f * pos[k];
#pragma unroll
    for (int m = 1; m < 64; m <<= 1) v += __shfl_xor(v, m);
    __shared__ float red[4];
    if ((threadIdx.x & 63) == 0) red[threadIdx.x >> 6] = v;
    __syncthreads();
    if (threadIdx.x == 0)
        atomicAdd(out, (red[0] + red[1] + red[2] + red[3]) *
                           (1.0f / (2.0f * BATCH)));
}

extern "C" void kernel_launch(void* const* d_in, const int* in_sizes, int n_in,
                              void* d_out, int out_size, void* d_ws, size_t ws_size,
                              hipStream_t stream) {
    const float* emb_i = (const float*)d_in[0];
    const float* emb_j = (const float*)d_in[1];
    float* out = (float*)d_out;

    char* ws = (char*)d_ws;
    bf16_t* zi   = (bf16_t*)(ws);                            // 1 MB
    bf16_t* zj   = (bf16_t*)(ws + (1u << 20));               // 1 MB
    float*  rowP = (float*)(ws + (2u << 20));                // 512 KB
    float*  colP = (float*)(ws + (2u << 20) + (512u << 10)); // 512 KB
    float*  pos  = (float*)(ws + (3u << 20));                // 16 KB

    normalize_kernel<<<BATCH / 4, 256, 0, stream>>>(emb_i, emb_j, zi, zj, pos, out);
    gemm_exp_kernel<<<dim3(NT, NT), 256, 0, stream>>>(zi, zj, rowP, colP);
    finalize_kernel<<<BATCH / 256, 256, 0, stream>>>(rowP, colP, pos, out);
}

// Round 11
// 89.934 us; speedup vs baseline: 1.0256x; 1.0256x over previous
//
#include <hip/hip_runtime.h>

#define BATCH 4096
#define DIM   128
#define NT    32   // 4096 / 128 tiles per dimension
// TEMP = 0.25 -> 1/T = 4; 4*log2(e):
#define EXP_SCALE 5.770780163555854f

typedef __bf16 bf16_t;
typedef __bf16 bf16x8 __attribute__((ext_vector_type(8)));
typedef float  f32x4  __attribute__((ext_vector_type(4)));

// ---------------------------------------------------------------------------
// MEASUREMENT ROUND: pipeline is byte-identical to the best config (R8,
// 74.4us) EXCEPT kernel B is launched TWICE, the second time into a
// scratch denominator region that is never read. dur_us - 74.4 isolates
// K2's true duration + one dispatch gap (our kernels have never appeared
// in the fill-dominated top-5, so this is the only way to attribute the
// ~33us non-fill budget between {K1,K2,K3} and harness reset overhead).
// ---------------------------------------------------------------------------

// ---------------------------------------------------------------------------
// Kernel A: per row k, normalize emb_i[k] and emb_j[k] (fp32 math), write
// bf16 z_i, z_j to workspace, pos[k] = cos-sim in fp32. One wave per row.
// Blocks 0..7 zero exactly the rowDenom/colDenom region (32 KB), race-free.
// ---------------------------------------------------------------------------
__global__ __launch_bounds__(256) void normalize_kernel(
    const float* __restrict__ emb_i, const float* __restrict__ emb_j,
    bf16_t* __restrict__ zi, bf16_t* __restrict__ zj, float* __restrict__ pos,
    float* __restrict__ denoms /* rowDenom(4096) ++ colDenom(4096) */)
{
    if (blockIdx.x < 8) {
        int idx = (blockIdx.x * 256 + threadIdx.x) * 4;
        *(float4*)&denoms[idx] = make_float4(0.f, 0.f, 0.f, 0.f);
    }

    int wave = threadIdx.x >> 6;
    int lane = threadIdx.x & 63;
    int k = blockIdx.x * 4 + wave;

    const float2* ei = (const float2*)(emb_i + (size_t)k * DIM);
    const float2* ej = (const float2*)(emb_j + (size_t)k * DIM);
    float2 a = ei[lane];
    float2 b = ej[lane];

    float sii = a.x * a.x + a.y * a.y;
    float sjj = b.x * b.x + b.y * b.y;
    float sij = a.x * b.x + a.y * b.y;
#pragma unroll
    for (int m = 1; m < 64; m <<= 1) {
        sii += __shfl_xor(sii, m);
        sjj += __shfl_xor(sjj, m);
        sij += __shfl_xor(sij, m);
    }
    float inv_i = 1.0f / fmaxf(sqrtf(sii), 1e-12f);
    float inv_j = 1.0f / fmaxf(sqrtf(sjj), 1e-12f);

    struct bf16_2 { bf16_t x, y; };
    bf16_2 pi, pj;
    pi.x = (bf16_t)(a.x * inv_i);  pi.y = (bf16_t)(a.y * inv_i);
    pj.x = (bf16_t)(b.x * inv_j);  pj.y = (bf16_t)(b.y * inv_j);
    ((bf16_2*)(zi + (size_t)k * DIM))[lane] = pi;
    ((bf16_2*)(zj + (size_t)k * DIM))[lane] = pj;

    if (lane == 0) pos[k] = sij * inv_i * inv_j;
}

// ---------------------------------------------------------------------------
// Kernel B: 128x128 tile of S = Zi * Zj^T per block (grid 32x32).
// Byte-identical to the proven 74.4us body: single-stage 72KB LDS,
// padded-136 rows (free 2-way bank pattern), no swizzle, no fences,
// atomic output path (empirically beats partials by ~18us, R10/R1).
// ---------------------------------------------------------------------------
__global__ __launch_bounds__(256) void gemm_exp_kernel(
    const bf16_t* __restrict__ zi, const bf16_t* __restrict__ zj,
    float* __restrict__ rowDenom, float* __restrict__ colDenom)
{
    __shared__ __align__(16) bf16_t zi_s[128][136];
    __shared__ __align__(16) bf16_t zj_s[128][136];
    __shared__ float colRed[4][128];

    const int tid = threadIdx.x;
    const int ti = blockIdx.x, tj = blockIdx.y;

    // Stage 128x128 bf16 of each matrix: 2048 16B-chunks / matrix, 8 iters.
#pragma unroll
    for (int it = 0; it < 8; ++it) {
        int c = it * 256 + tid;
        int row = c >> 4;          // 16 chunks per row
        int col = (c & 15) << 3;   // 8 bf16 per chunk
        *(uint4*)&zi_s[row][col] =
            *(const uint4*)(zi + ((size_t)(ti * 128 + row)) * DIM + col);
        *(uint4*)&zj_s[row][col] =
            *(const uint4*)(zj + ((size_t)(tj * 128 + row)) * DIM + col);
    }
    __syncthreads();

    const int wave = tid >> 6;
    const int lane = tid & 63;
    const int l15  = lane & 15;
    const int quad = lane >> 4;

    const f32x4 vzero = {0.f, 0.f, 0.f, 0.f};
    f32x4 acc[2][8];
#pragma unroll
    for (int rt = 0; rt < 2; ++rt)
#pragma unroll
        for (int ct = 0; ct < 8; ++ct) acc[rt][ct] = vzero;

#pragma unroll
    for (int ks = 0; ks < 4; ++ks) {
        int k0 = ks * 32 + quad * 8;
        bf16x8 afrag[2], bfrag[8];
#pragma unroll
        for (int rt = 0; rt < 2; ++rt)
            afrag[rt] = *(const bf16x8*)&zi_s[(wave * 2 + rt) * 16 + l15][k0];
#pragma unroll
        for (int ct = 0; ct < 8; ++ct)
            bfrag[ct] = *(const bf16x8*)&zj_s[ct * 16 + l15][k0];
#pragma unroll
        for (int rt = 0; rt < 2; ++rt)
#pragma unroll
            for (int ct = 0; ct < 8; ++ct)
                acc[rt][ct] = __builtin_amdgcn_mfma_f32_16x16x32_bf16(
                    afrag[rt], bfrag[ct], acc[rt][ct], 0, 0, 0);
    }

    // Epilogue: exp and partial sums.
    float rowPart[2][4] = {{0.f, 0.f, 0.f, 0.f}, {0.f, 0.f, 0.f, 0.f}};
    float colPart[8]    = {0.f, 0.f, 0.f, 0.f, 0.f, 0.f, 0.f, 0.f};
#pragma unroll
    for (int rt = 0; rt < 2; ++rt)
#pragma unroll
        for (int ct = 0; ct < 8; ++ct)
#pragma unroll
            for (int r = 0; r < 4; ++r) {
                float e = exp2f(acc[rt][ct][r] * EXP_SCALE);
                rowPart[rt][r] += e;   // row = (wave*2+rt)*16 + quad*4 + r
                colPart[ct]    += e;   // col = ct*16 + l15
            }

    // Row sums: 16-lane shfl reduce -> one atomic per row per block.
#pragma unroll
    for (int rt = 0; rt < 2; ++rt)
#pragma unroll
        for (int r = 0; r < 4; ++r) {
            float v = rowPart[rt][r];
            v += __shfl_xor(v, 1);
            v += __shfl_xor(v, 2);
            v += __shfl_xor(v, 4);
            v += __shfl_xor(v, 8);
            if (l15 == 0) {
                int grow = ti * 128 + (wave * 2 + rt) * 16 + quad * 4 + r;
                atomicAdd(&rowDenom[grow], v);
            }
        }

    // Col sums: quad shfl-reduce, cross-wave LDS reduce, 128 coalesced
    // atomics per block.
#pragma unroll
    for (int ct = 0; ct < 8; ++ct) {
        float v = colPart[ct];
        v += __shfl_xor(v, 16);
        v += __shfl_xor(v, 32);
        if (quad == 0) colRed[wave][ct * 16 + l15] = v;
    }
    __syncthreads();
    if (tid < 128) {
        float s = colRed[0][tid] + colRed[1][tid] + colRed[2][tid] + colRed[3][tid];
        atomicAdd(&colDenom[tj * 128 + tid], s);
    }
}

// ---------------------------------------------------------------------------
// Kernel C: 1 block x 1024 threads; 3 independent float4 loads per thread,
// 8 logf, wave shfl-reduce, 16-way LDS reduce (R8 version, measured-null
// vs the 256-thread serial version -- kept as-is).
// ---------------------------------------------------------------------------
__global__ __launch_bounds__(1024) void finalize_kernel(
    const float* __restrict__ denoms, const float* __restrict__ pos,
    float* __restrict__ out)
{
    const float4* rowD4 = (const float4*)denoms;            // 1024 float4
    const float4* colD4 = (const float4*)(denoms + BATCH);  // 1024 float4
    const float4* pos4  = (const float4*)pos;               // 1024 float4

    const int tid  = threadIdx.x;
    const int lane = tid & 63;
    const int wv   = tid >> 6;

    float4 rd = rowD4[tid];
    float4 cd = colD4[tid];
    float4 p  = pos4[tid];

    float acc = logf(rd.x) + logf(rd.y) + logf(rd.z) + logf(rd.w)
              + logf(cd.x) + logf(cd.y) + logf(cd.z) + logf(cd.w)
              - 8.0f * (p.x + p.y + p.z + p.w);

#pragma unroll
    for (int m = 1; m < 64; m <<= 1) acc += __shfl_xor(acc, m);

    __shared__ float red[16];
    if (lane == 0) red[wv] = acc;
    __syncthreads();
    if (wv == 0) {
        float v = (lane < 16) ? red[lane] : 0.0f;
#pragma unroll
        for (int m = 1; m < 64; m <<= 1) v += __shfl_xor(v, m);
        if (lane == 0) out[0] = v * (1.0f / (2.0f * BATCH));
    }
}

extern "C" void kernel_launch(void* const* d_in, const int* in_sizes, int n_in,
                              void* d_out, int out_size, void* d_ws, size_t ws_size,
                              hipStream_t stream) {
    const float* emb_i = (const float*)d_in[0];
    const float* emb_j = (const float*)d_in[1];
    float* out = (float*)d_out;

    char* ws = (char*)d_ws;
    bf16_t* zi      = (bf16_t*)(ws);                 // 1 MB
    bf16_t* zj      = (bf16_t*)(ws + (1u << 20));    // 1 MB
    float*  denoms  = (float*)(ws + (2u << 20));     // 32 KB (row ++ col)
    float*  pos     = denoms + 2 * BATCH;            // 16 KB
    float*  denoms2 = (float*)(ws + (4u << 20));     // 32 KB scratch (probe)

    normalize_kernel<<<BATCH / 4, 256, 0, stream>>>(emb_i, emb_j, zi, zj, pos, denoms);
    // Real K2:
    gemm_exp_kernel<<<dim3(NT, NT), 256, 0, stream>>>(zi, zj, denoms, denoms + BATCH);
    // Probe K2 (identical work, scratch output, never read):
    gemm_exp_kernel<<<dim3(NT, NT), 256, 0, stream>>>(zi, zj, denoms2, denoms2 + BATCH);
    finalize_kernel<<<1, 1024, 0, stream>>>(denoms, pos, out);
}